// Round 1
// baseline (1262.026 us; speedup 1.0000x reference)
//
#include <hip/hip_runtime.h>
#include <math.h>

// AdaptedMixer (mamba-style) — Round 1: correct fp32 pipeline.
// B=2 S=2048 Dm=768 I=1536 N=16 R=48 K=4
// ws layout (floats): hidden[B*I*S] | sgate[B*I*S] | h[B*I*S] | dt[B*I*S] | ssmp[4096*80]
// y reuses hidden (hidden only consumed by conv kernel). Total ~102 MB.

static constexpr int S_LEN  = 2048;
static constexpr int DMODEL = 768;
static constexpr int ICH    = 1536;
static constexpr int NST    = 16;

__device__ __forceinline__ float silu_f(float x) {
    return x / (1.0f + __expf(-x));
}

// ---------------- K1: in_proj GEMM: [4096,768] @ [768,3072]^T -> hidden/sgate [B][I][S]
__global__ __launch_bounds__(256) void k1_inproj(
    const float* __restrict__ X,   // [4096][768]
    const float* __restrict__ W,   // [3072][768]
    float* __restrict__ hidden,    // [B][I][S]
    float* __restrict__ sgate)     // [B][I][S] (silu applied)
{
    __shared__ float4 As[64][5];   // [m][k4], row stride 20 floats (2-way bank max)
    __shared__ float4 Bs[64][5];   // [n][k4]
    const int tid = threadIdx.x;
    const int tx = tid & 15;       // m lane (s-coalesced on store)
    const int ty = tid >> 4;       // n group
    const int m0 = blockIdx.x * 64;
    const int n0 = blockIdx.y * 64;
    const int lrow = tid >> 2, lc4 = tid & 3;

    float acc[4][4] = {};
    for (int k0 = 0; k0 < 768; k0 += 16) {
        As[lrow][lc4] = *(const float4*)(X + (size_t)(m0 + lrow) * 768 + k0 + lc4 * 4);
        Bs[lrow][lc4] = *(const float4*)(W + (size_t)(n0 + lrow) * 768 + k0 + lc4 * 4);
        __syncthreads();
        #pragma unroll
        for (int kk4 = 0; kk4 < 4; ++kk4) {
            float4 a[4], b[4];
            #pragma unroll
            for (int i = 0; i < 4; ++i) a[i] = As[tx + 16 * i][kk4];
            #pragma unroll
            for (int j = 0; j < 4; ++j) b[j] = Bs[ty + 16 * j][kk4];
            #pragma unroll
            for (int i = 0; i < 4; ++i)
                #pragma unroll
                for (int j = 0; j < 4; ++j)
                    acc[i][j] += a[i].x * b[j].x + a[i].y * b[j].y +
                                 a[i].z * b[j].z + a[i].w * b[j].w;
        }
        __syncthreads();
    }
    #pragma unroll
    for (int i = 0; i < 4; ++i) {
        int m = m0 + tx + 16 * i;
        int b = m >> 11, s = m & 2047;
        #pragma unroll
        for (int j = 0; j < 4; ++j) {
            int e = n0 + ty + 16 * j;
            float v = acc[i][j];
            if (e < ICH) hidden[((size_t)b * ICH + e) * S_LEN + s] = v;
            else         sgate[((size_t)b * ICH + (e - ICH)) * S_LEN + s] = silu_f(v);
        }
    }
}

// ---------------- K2: causal depthwise conv (K=4) + bias + silu
__global__ __launch_bounds__(256) void k2_conv(
    const float* __restrict__ hidden,
    const float* __restrict__ conv_w,  // [I][4]
    const float* __restrict__ conv_b,  // [I]
    float* __restrict__ h)
{
    int idx = blockIdx.x * 256 + threadIdx.x;      // over B*I*S
    int s = idx & (S_LEN - 1);
    int bi = idx >> 11;
    int i = (bi >= ICH) ? bi - ICH : bi;           // B==2
    const float* hp = hidden + (size_t)bi * S_LEN;
    float w0 = conv_w[i * 4 + 0], w1 = conv_w[i * 4 + 1];
    float w2 = conv_w[i * 4 + 2], w3 = conv_w[i * 4 + 3];
    float acc = conv_b[i];
    if (s >= 3) acc += w0 * hp[s - 3];
    if (s >= 2) acc += w1 * hp[s - 2];
    if (s >= 1) acc += w2 * hp[s - 1];
    acc += w3 * hp[s];
    h[idx] = silu_f(acc);
}

// ---------------- K3: x_proj: ssmp[m][e] += sum_i h[b,i,s]*xw[e,i]  (K-split x8, atomics)
__global__ __launch_bounds__(256) void k3_xproj(
    const float* __restrict__ h,   // [B][I][S]
    const float* __restrict__ xw,  // [80][1536]
    float* __restrict__ ssmp)      // [4096][80], pre-zeroed
{
    const int tid = threadIdx.x;
    const int txs = tid & 31;      // 4-s group
    const int tye = tid >> 5;      // 0..7
    const int m0 = blockIdx.x * 128;
    const int b = m0 >> 11;
    const int s_base = (m0 & 2047) + txs * 4;
    const int i0 = blockIdx.y * 192;
    float acc[10][4] = {};
    #pragma unroll 2
    for (int i = i0; i < i0 + 192; ++i) {
        float4 hv = *(const float4*)(h + ((size_t)b * ICH + i) * S_LEN + s_base);
        #pragma unroll
        for (int j = 0; j < 10; ++j) {
            float wv = xw[(size_t)(tye + 8 * j) * ICH + i];
            acc[j][0] += wv * hv.x; acc[j][1] += wv * hv.y;
            acc[j][2] += wv * hv.z; acc[j][3] += wv * hv.w;
        }
    }
    #pragma unroll
    for (int j = 0; j < 10; ++j) {
        int e = tye + 8 * j;
        #pragma unroll
        for (int r = 0; r < 4; ++r)
            atomicAdd(ssmp + (size_t)(m0 + txs * 4 + r) * 80 + e, acc[j][r]);
    }
}

// ---------------- K4: dt = softplus(ts @ dtw^T + b), alpha at s=S-1, write [B][I][S]
__global__ __launch_bounds__(256) void k4_dt(
    const float* __restrict__ ssmp,   // [4096][80] (ts = cols 0..47)
    const float* __restrict__ dtw,    // [1536][48]
    const float* __restrict__ dtb,    // [1536]
    const float* __restrict__ alpha,  // [1536]
    float* __restrict__ dt)           // [B][I][S]
{
    __shared__ float4 Ts[64][13];
    __shared__ float4 Ws[64][13];
    const int tid = threadIdx.x;
    const int tx = tid & 15;
    const int ty = tid >> 4;
    const int m0 = blockIdx.x * 64;
    const int n0 = blockIdx.y * 64;
    for (int t = tid; t < 768; t += 256) {
        int row = t / 12, c4 = t % 12;
        Ts[row][c4] = *(const float4*)(ssmp + (size_t)(m0 + row) * 80 + c4 * 4);
        Ws[row][c4] = *(const float4*)(dtw + (size_t)(n0 + row) * 48 + c4 * 4);
    }
    __syncthreads();
    float acc[4][4] = {};
    #pragma unroll
    for (int kk4 = 0; kk4 < 12; ++kk4) {
        float4 a[4], b[4];
        #pragma unroll
        for (int i = 0; i < 4; ++i) a[i] = Ts[tx + 16 * i][kk4];
        #pragma unroll
        for (int j = 0; j < 4; ++j) b[j] = Ws[ty + 16 * j][kk4];
        #pragma unroll
        for (int i = 0; i < 4; ++i)
            #pragma unroll
            for (int j = 0; j < 4; ++j)
                acc[i][j] += a[i].x * b[j].x + a[i].y * b[j].y +
                             a[i].z * b[j].z + a[i].w * b[j].w;
    }
    #pragma unroll
    for (int i = 0; i < 4; ++i) {
        int m = m0 + tx + 16 * i;
        int b = m >> 11, s = m & 2047;
        #pragma unroll
        for (int j = 0; j < 4; ++j) {
            int e = n0 + ty + 16 * j;
            float x = acc[i][j] + dtb[e];
            float sp = (x > 20.0f) ? x : log1pf(expf(x));
            if (s == S_LEN - 1) sp *= alpha[e];
            dt[((size_t)b * ICH + e) * S_LEN + s] = sp;
        }
    }
}

// ---------------- K5: sequential SSM scan. 16 lanes per (b,i) chain, LDS-staged 64-step chunks.
__global__ __launch_bounds__(256) void k5_scan(
    const float* __restrict__ dt,    // [B][I][S]
    const float* __restrict__ h,     // [B][I][S]
    const float* __restrict__ sgate, // [B][I][S] (silu'd)
    const float* __restrict__ ssmp,  // [4096][80]: B=48..63, C=64..79
    const float* __restrict__ A_log, // [I][16]
    const float* __restrict__ Dp,    // [I]
    const float* __restrict__ fg,    // [I]
    float* __restrict__ yout)        // [B][I][S]
{
    __shared__ float dt_s[16][68];   // +4 pad: chain-stride 68 -> banks (4c+t), conflict-free
    __shared__ float h_s[16][68];
    __shared__ float g_s[16][68];
    __shared__ float y_s[16][68];
    __shared__ float Bc[64][16];     // [s][n] — all chains read same word: broadcast
    __shared__ float Cc[64][16];
    const int tid = threadIdx.x;
    const int c = tid >> 4;          // chain local 0..15
    const int n = tid & 15;
    const int b = blockIdx.y;
    const int i = blockIdx.x * 16 + c;
    const size_t row_base = ((size_t)b * ICH + blockIdx.x * 16 + (tid >> 4)) * S_LEN;
    const int scol = (tid & 15) * 4;
    const int prow = tid >> 2, pc4 = (tid & 3) * 4;
    const float Apr = -expf(A_log[i * NST + n]) * 1.44269504088896f; // A*log2(e)
    const float Dv = Dp[i];
    const float fgv = fg[i];
    float state = 0.0f;

    for (int s0 = 0; s0 < S_LEN; s0 += 64) {
        __syncthreads();  // previous chunk's y_s store done
        *(float4*)&dt_s[c][scol] = *(const float4*)(dt    + row_base + s0 + scol);
        *(float4*)&h_s[c][scol]  = *(const float4*)(h     + row_base + s0 + scol);
        *(float4*)&g_s[c][scol]  = *(const float4*)(sgate + row_base + s0 + scol);
        *(float4*)&Bc[prow][pc4] = *(const float4*)(ssmp + (size_t)(b * S_LEN + s0 + prow) * 80 + 48 + pc4);
        *(float4*)&Cc[prow][pc4] = *(const float4*)(ssmp + (size_t)(b * S_LEN + s0 + prow) * 80 + 64 + pc4);
        __syncthreads();
        for (int t = 0; t < 64; ++t) {
            float dtv = dt_s[c][t];
            float hv  = h_s[c][t];
            float dA  = exp2f(Apr * dtv);
            float x   = dtv * hv * Bc[t][n];
            state = fmaf(dA, state, x);
            float yp = state * Cc[t][n];
            yp += __shfl_xor(yp, 1, 16);
            yp += __shfl_xor(yp, 2, 16);
            yp += __shfl_xor(yp, 4, 16);
            yp += __shfl_xor(yp, 8, 16);
            if (n == 0) {
                float yv = fmaf(hv, Dv, yp) * g_s[c][t];
                if (s0 + t == S_LEN - 1) yv *= fgv;
                y_s[c][t] = yv;
            }
        }
        __syncthreads();
        *(float4*)(yout + row_base + s0 + scol) = *(const float4*)&y_s[c][scol];
    }
}

// ---------------- K6: out[m][d] = sum_i y[b,i,s]*ow[d,i]  (A transposed-staged via LDS)
__global__ __launch_bounds__(256) void k6_outproj(
    const float* __restrict__ y,   // [B][I][S]
    const float* __restrict__ W,   // [768][1536]
    float* __restrict__ out)       // [4096][768]
{
    __shared__ float As[64][20];   // [s][k], stride 20 floats
    __shared__ float4 Bs[64][5];   // [d][k4]
    const int tid = threadIdx.x;
    const int tn = tid & 15;       // d lane (coalesced store)
    const int tm = tid >> 4;       // m group
    const int m0 = blockIdx.x * 64;
    const int n0 = blockIdx.y * 64;
    const int b = m0 >> 11, s0 = m0 & 2047;
    const int kk_ld = tid >> 4;          // 0..15 (k row for A stage)
    const int sc4 = (tid & 15) * 4;      // s group for A stage
    const int brow = tid >> 2, bc4 = tid & 3;
    float acc[4][4] = {};
    for (int k0 = 0; k0 < ICH; k0 += 16) {
        float4 av = *(const float4*)(y + ((size_t)b * ICH + k0 + kk_ld) * S_LEN + s0 + sc4);
        float4 bv = *(const float4*)(W + (size_t)(n0 + brow) * ICH + k0 + bc4 * 4);
        __syncthreads();
        As[sc4 + 0][kk_ld] = av.x;
        As[sc4 + 1][kk_ld] = av.y;
        As[sc4 + 2][kk_ld] = av.z;
        As[sc4 + 3][kk_ld] = av.w;
        Bs[brow][bc4] = bv;
        __syncthreads();
        #pragma unroll
        for (int kk4 = 0; kk4 < 4; ++kk4) {
            float4 a[4], bb[4];
            #pragma unroll
            for (int i = 0; i < 4; ++i) a[i] = *(const float4*)&As[tm + 16 * i][kk4 * 4];
            #pragma unroll
            for (int j = 0; j < 4; ++j) bb[j] = Bs[tn + 16 * j][kk4];
            #pragma unroll
            for (int i = 0; i < 4; ++i)
                #pragma unroll
                for (int j = 0; j < 4; ++j)
                    acc[i][j] += a[i].x * bb[j].x + a[i].y * bb[j].y +
                                 a[i].z * bb[j].z + a[i].w * bb[j].w;
        }
    }
    #pragma unroll
    for (int i = 0; i < 4; ++i) {
        int m = m0 + tm + 16 * i;
        #pragma unroll
        for (int j = 0; j < 4; ++j)
            out[(size_t)m * DMODEL + n0 + tn + 16 * j] = acc[i][j];
    }
}

extern "C" void kernel_launch(void* const* d_in, const int* in_sizes, int n_in,
                              void* d_out, int out_size, void* d_ws, size_t ws_size,
                              hipStream_t stream) {
    const float* X     = (const float*)d_in[0];
    const float* W1    = (const float*)d_in[1];
    const float* CW    = (const float*)d_in[2];
    const float* CB    = (const float*)d_in[3];
    const float* XW    = (const float*)d_in[4];
    const float* DTW   = (const float*)d_in[5];
    const float* DTB   = (const float*)d_in[6];
    const float* ALOG  = (const float*)d_in[7];
    const float* DD    = (const float*)d_in[8];
    const float* OW    = (const float*)d_in[9];
    const float* ALPHA = (const float*)d_in[10];
    const float* FG    = (const float*)d_in[11];
    float* out = (float*)d_out;

    float* ws = (float*)d_ws;
    const size_t NBIS = (size_t)2 * ICH * S_LEN;  // 6,291,456
    float* hidden = ws;
    float* sgate  = hidden + NBIS;
    float* hbuf   = sgate + NBIS;
    float* dtbuf  = hbuf + NBIS;
    float* ssmp   = dtbuf + NBIS;                 // 4096*80
    float* ybuf   = hidden;                       // reuse: hidden dead after k2

    hipMemsetAsync(ssmp, 0, (size_t)4096 * 80 * sizeof(float), stream);
    k1_inproj<<<dim3(64, 48), 256, 0, stream>>>(X, W1, hidden, sgate);
    k2_conv<<<dim3((2 * ICH * S_LEN) / 256), 256, 0, stream>>>(hidden, CW, CB, hbuf);
    k3_xproj<<<dim3(32, 8), 256, 0, stream>>>(hbuf, XW, ssmp);
    k4_dt<<<dim3(64, 24), 256, 0, stream>>>(ssmp, DTW, DTB, ALPHA, dtbuf);
    k5_scan<<<dim3(96, 2), 256, 0, stream>>>(dtbuf, hbuf, sgate, ssmp, ALOG, DD, FG, ybuf);
    k6_outproj<<<dim3(64, 12), 256, 0, stream>>>(ybuf, OW, out);
}

// Round 3
// 806.295 us; speedup vs baseline: 1.5652x; 1.5652x over previous
//
#include <hip/hip_runtime.h>
#include <math.h>

// AdaptedMixer — Round 2 (resubmit; R2 bench was GPU-acquisition timeout).
// [B][S][I] layout everywhere + 3-phase chunked scan.
// B=2 S=2048 Dm=768 I=1536 N=16 R=48 K=4.  M = B*S = 4096.
// ws (floats): hidden[M*I] | sgate[M*I] | h[M*I] | dt[M*I] (y written in place) | ssmp[M*80]
// chunk-summary arrays (P, Sf, CIn: 1.57M floats each) overlay the dead hidden buffer.

static constexpr int S_LEN  = 2048;
static constexpr int DMODEL = 768;
static constexpr int ICH    = 1536;
static constexpr int NST    = 16;
static constexpr int MROWS  = 4096;   // B*S
static constexpr int NCH    = 32;     // chunks
static constexpr int CHS    = 64;     // steps per chunk

__device__ __forceinline__ float silu_f(float x) {
    return x / (1.0f + __expf(-x));
}

// ---------------- K1: in_proj GEMM: [4096,768] @ [3072,768]^T -> hidden/sgate [M][I]
__global__ __launch_bounds__(256) void k1_inproj(
    const float* __restrict__ X,   // [4096][768]
    const float* __restrict__ W,   // [3072][768]
    float* __restrict__ hidden,    // [M][I]
    float* __restrict__ sgate)     // [M][I] (silu applied)
{
    __shared__ float4 As[64][5];
    __shared__ float4 Bs[64][5];
    const int tid = threadIdx.x;
    const int tn = tid & 15;       // e lane (store-coalesced)
    const int tm = tid >> 4;       // m group
    const int m0 = blockIdx.x * 64;
    const int n0 = blockIdx.y * 64;
    const int lrow = tid >> 2, lc4 = tid & 3;

    float acc[4][4] = {};
    for (int k0 = 0; k0 < 768; k0 += 16) {
        As[lrow][lc4] = *(const float4*)(X + (size_t)(m0 + lrow) * 768 + k0 + lc4 * 4);
        Bs[lrow][lc4] = *(const float4*)(W + (size_t)(n0 + lrow) * 768 + k0 + lc4 * 4);
        __syncthreads();
        #pragma unroll
        for (int kk4 = 0; kk4 < 4; ++kk4) {
            float4 a[4], b[4];
            #pragma unroll
            for (int i = 0; i < 4; ++i) a[i] = As[tm + 16 * i][kk4];
            #pragma unroll
            for (int j = 0; j < 4; ++j) b[j] = Bs[tn + 16 * j][kk4];
            #pragma unroll
            for (int i = 0; i < 4; ++i)
                #pragma unroll
                for (int j = 0; j < 4; ++j)
                    acc[i][j] += a[i].x * b[j].x + a[i].y * b[j].y +
                                 a[i].z * b[j].z + a[i].w * b[j].w;
        }
        __syncthreads();
    }
    const bool isGate = (n0 >= ICH);
    #pragma unroll
    for (int i = 0; i < 4; ++i) {
        int m = m0 + tm + 16 * i;
        #pragma unroll
        for (int j = 0; j < 4; ++j) {
            int e = n0 + tn + 16 * j;
            float v = acc[i][j];
            if (!isGate) hidden[(size_t)m * ICH + e] = v;
            else         sgate[(size_t)m * ICH + (e - ICH)] = silu_f(v);
        }
    }
}

// ---------------- K2: causal depthwise conv (K=4) + bias + silu, [M][I] layout
__global__ __launch_bounds__(256) void k2_conv(
    const float* __restrict__ hidden,  // [M][I]
    const float* __restrict__ conv_w,  // [I][4]
    const float* __restrict__ conv_b,  // [I]
    float* __restrict__ h)             // [M][I]
{
    int idx = blockIdx.x * 256 + threadIdx.x;      // over M * (I/4)
    int i4 = idx % 384;
    int m  = idx / 384;
    int s  = m & (S_LEN - 1);
    const float* base = hidden + (size_t)m * ICH + i4 * 4;
    const int c0 = i4 * 4;
    float4 wa = *(const float4*)(conv_w + (c0 + 0) * 4);
    float4 wb = *(const float4*)(conv_w + (c0 + 1) * 4);
    float4 wc = *(const float4*)(conv_w + (c0 + 2) * 4);
    float4 wd = *(const float4*)(conv_w + (c0 + 3) * 4);
    float4 bv = *(const float4*)(conv_b + c0);
    float4 z = {0.f, 0.f, 0.f, 0.f};
    float4 x0 = *(const float4*)(base);
    float4 x1 = (s >= 1) ? *(const float4*)(base - ICH)     : z;
    float4 x2 = (s >= 2) ? *(const float4*)(base - 2 * ICH) : z;
    float4 x3 = (s >= 3) ? *(const float4*)(base - 3 * ICH) : z;
    float4 r;
    r.x = bv.x + wa.x * x3.x + wa.y * x2.x + wa.z * x1.x + wa.w * x0.x;
    r.y = bv.y + wb.x * x3.y + wb.y * x2.y + wb.z * x1.y + wb.w * x0.y;
    r.z = bv.z + wc.x * x3.z + wc.y * x2.z + wc.z * x1.z + wc.w * x0.z;
    r.w = bv.w + wd.x * x3.w + wd.y * x2.w + wd.z * x1.w + wd.w * x0.w;
    r.x = silu_f(r.x); r.y = silu_f(r.y); r.z = silu_f(r.z); r.w = silu_f(r.w);
    *(float4*)(h + (size_t)m * ICH + i4 * 4) = r;
}

// ---------------- K3: x_proj GEMM: ssmp[m][e] += h[m][:] . xw[e][:], K-split x4 atomics
__global__ __launch_bounds__(256) void k3_xproj(
    const float* __restrict__ h,   // [M][I]
    const float* __restrict__ xw,  // [80][I]
    float* __restrict__ ssmp)      // [M][80], pre-zeroed
{
    __shared__ float4 As[64][5];   // [m][k4]
    __shared__ float4 Bs[80][5];   // [e][k4]
    const int tid = threadIdx.x;
    const int tm = tid >> 4;       // m group 0..15
    const int te = tid & 15;       // e lane 0..15
    const int m0 = blockIdx.x * 64;
    const int k_beg = blockIdx.y * 384;
    const int lrow = tid >> 2, lc4 = tid & 3;
    float4 acc[4][5] = {};
    for (int k0 = k_beg; k0 < k_beg + 384; k0 += 16) {
        As[lrow][lc4] = *(const float4*)(h + (size_t)(m0 + lrow) * ICH + k0 + lc4 * 4);
        for (int t = tid; t < 320; t += 256)
            Bs[t >> 2][t & 3] = *(const float4*)(xw + (size_t)(t >> 2) * ICH + k0 + (t & 3) * 4);
        __syncthreads();
        #pragma unroll
        for (int kk4 = 0; kk4 < 4; ++kk4) {
            float4 a[4], b[5];
            #pragma unroll
            for (int i = 0; i < 4; ++i) a[i] = As[tm + 16 * i][kk4];
            #pragma unroll
            for (int j = 0; j < 5; ++j) b[j] = Bs[te + 16 * j][kk4];
            #pragma unroll
            for (int i = 0; i < 4; ++i)
                #pragma unroll
                for (int j = 0; j < 5; ++j) {
                    acc[i][j].x += a[i].x * b[j].x; acc[i][j].y += a[i].y * b[j].y;
                    acc[i][j].z += a[i].z * b[j].z; acc[i][j].w += a[i].w * b[j].w;
                }
        }
        __syncthreads();
    }
    #pragma unroll
    for (int i = 0; i < 4; ++i) {
        int m = m0 + tm + 16 * i;
        #pragma unroll
        for (int j = 0; j < 5; ++j) {
            float v = acc[i][j].x + acc[i][j].y + acc[i][j].z + acc[i][j].w;
            atomicAdd(ssmp + (size_t)m * 80 + te + 16 * j, v);
        }
    }
}

// ---------------- K4: dt = softplus(ts @ dtw^T + b), alpha at s=S-1, write [M][I]
__global__ __launch_bounds__(256) void k4_dt(
    const float* __restrict__ ssmp,   // [M][80] (ts = cols 0..47)
    const float* __restrict__ dtw,    // [I][48]
    const float* __restrict__ dtb,    // [I]
    const float* __restrict__ alpha,  // [I]
    float* __restrict__ dt)           // [M][I]
{
    __shared__ float4 Ts[64][13];
    __shared__ float4 Ws[64][13];
    const int tid = threadIdx.x;
    const int tm = tid >> 4;
    const int te = tid & 15;
    const int m0 = blockIdx.x * 64;
    const int n0 = blockIdx.y * 64;
    for (int t = tid; t < 768; t += 256) {
        int row = t / 12, c4 = t % 12;
        Ts[row][c4] = *(const float4*)(ssmp + (size_t)(m0 + row) * 80 + c4 * 4);
        Ws[row][c4] = *(const float4*)(dtw + (size_t)(n0 + row) * 48 + c4 * 4);
    }
    __syncthreads();
    float acc[4][4] = {};
    #pragma unroll
    for (int kk4 = 0; kk4 < 12; ++kk4) {
        float4 a[4], b[4];
        #pragma unroll
        for (int i = 0; i < 4; ++i) a[i] = Ts[tm + 16 * i][kk4];
        #pragma unroll
        for (int j = 0; j < 4; ++j) b[j] = Ws[te + 16 * j][kk4];
        #pragma unroll
        for (int i = 0; i < 4; ++i)
            #pragma unroll
            for (int j = 0; j < 4; ++j)
                acc[i][j] += a[i].x * b[j].x + a[i].y * b[j].y +
                             a[i].z * b[j].z + a[i].w * b[j].w;
    }
    #pragma unroll
    for (int i = 0; i < 4; ++i) {
        int m = m0 + tm + 16 * i;
        int s = m & (S_LEN - 1);
        #pragma unroll
        for (int j = 0; j < 4; ++j) {
            int e = n0 + te + 16 * j;
            float x = acc[i][j] + dtb[e];
            float sp = (x > 20.0f) ? x : log1pf(expf(x));
            if (s == S_LEN - 1) sp *= alpha[e];
            dt[(size_t)m * ICH + e] = sp;
        }
    }
}

// ---------------- K5a: scan phase A — per-chunk summary (P = prod dA, Sf = local final state)
// grid (I/64, NCH, B), block 256 = 64 chains x 4 n-lanes
__global__ __launch_bounds__(256) void k5a_chunk(
    const float* __restrict__ dt,    // [M][I]
    const float* __restrict__ h,     // [M][I]
    const float* __restrict__ ssmp,  // [M][80]: B cols 48..63
    const float* __restrict__ A_log, // [I][16]
    float* __restrict__ PArr,        // [B*I*16][32]
    float* __restrict__ SfArr)       // [B*I*16][32]
{
    const int tid = threadIdx.x;
    const int n4 = tid & 3;
    const int il = tid >> 2;
    const int i = blockIdx.x * 64 + il;
    const int c = blockIdx.y;
    const int b = blockIdx.z;
    const int s0 = c * CHS;
    float4 alv = *(const float4*)(A_log + i * NST + n4 * 4);
    const float L2E = 1.44269504088896f;
    float Apr[4] = { -expf(alv.x) * L2E, -expf(alv.y) * L2E,
                     -expf(alv.z) * L2E, -expf(alv.w) * L2E };
    float st[4] = {0.f, 0.f, 0.f, 0.f};
    float P[4] = {1.f, 1.f, 1.f, 1.f};
    const float* dtp = dt + (size_t)(b * S_LEN + s0) * ICH + i;
    const float* hp  = h  + (size_t)(b * S_LEN + s0) * ICH + i;
    const float* Bp  = ssmp + (size_t)(b * S_LEN + s0) * 80 + 48 + n4 * 4;
    #pragma unroll 4
    for (int t = 0; t < CHS; ++t) {
        float dtv = dtp[(size_t)t * ICH];
        float hv  = hp[(size_t)t * ICH];
        float4 Bv = *(const float4*)(Bp + (size_t)t * 80);
        float x = dtv * hv;
        float dA0 = exp2f(Apr[0] * dtv);
        float dA1 = exp2f(Apr[1] * dtv);
        float dA2 = exp2f(Apr[2] * dtv);
        float dA3 = exp2f(Apr[3] * dtv);
        P[0] *= dA0; P[1] *= dA1; P[2] *= dA2; P[3] *= dA3;
        st[0] = fmaf(dA0, st[0], x * Bv.x);
        st[1] = fmaf(dA1, st[1], x * Bv.y);
        st[2] = fmaf(dA2, st[2], x * Bv.z);
        st[3] = fmaf(dA3, st[3], x * Bv.w);
    }
    size_t base = ((size_t)(b * ICH + i) * NST + n4 * 4) * NCH + c;
    #pragma unroll
    for (int j = 0; j < 4; ++j) {
        PArr[base + (size_t)j * NCH]  = P[j];
        SfArr[base + (size_t)j * NCH] = st[j];
    }
}

// ---------------- K5b: scan phase B — combine chunk summaries into carry-in per chunk
__global__ __launch_bounds__(256) void k5b_carry(
    const float* __restrict__ PArr,
    const float* __restrict__ SfArr,
    float* __restrict__ CIn)
{
    int idx = blockIdx.x * 256 + threadIdx.x;   // over B*I*16 = 49152
    size_t base = (size_t)idx * NCH;
    float carry = 0.f;
    #pragma unroll
    for (int c = 0; c < NCH; ++c) {
        CIn[base + c] = carry;
        carry = fmaf(PArr[base + c], carry, SfArr[base + c]);
    }
}

// ---------------- K5c: scan phase C — replay chunk with carry-in, emit y (over dt buffer)
__global__ __launch_bounds__(256) void k5c_emit(
    float* __restrict__ dt,          // [M][I]  (y written in place)
    const float* __restrict__ h,     // [M][I]
    const float* __restrict__ sgate, // [M][I]
    const float* __restrict__ ssmp,  // [M][80]: B 48..63, C 64..79
    const float* __restrict__ A_log, // [I][16]
    const float* __restrict__ Dp,    // [I]
    const float* __restrict__ fg,    // [I]
    const float* __restrict__ CIn)   // [B*I*16][32]
{
    const int tid = threadIdx.x;
    const int n4 = tid & 3;
    const int il = tid >> 2;
    const int i = blockIdx.x * 64 + il;
    const int c = blockIdx.y;
    const int b = blockIdx.z;
    const int s0 = c * CHS;
    float4 alv = *(const float4*)(A_log + i * NST + n4 * 4);
    const float L2E = 1.44269504088896f;
    float Apr[4] = { -expf(alv.x) * L2E, -expf(alv.y) * L2E,
                     -expf(alv.z) * L2E, -expf(alv.w) * L2E };
    const float Dv = Dp[i];
    const float fgv = fg[i];
    size_t cbase = ((size_t)(b * ICH + i) * NST + n4 * 4) * NCH + c;
    float st[4] = { CIn[cbase], CIn[cbase + NCH], CIn[cbase + 2 * NCH], CIn[cbase + 3 * NCH] };
    float* dtp = dt + (size_t)(b * S_LEN + s0) * ICH + i;
    const float* hp  = h     + (size_t)(b * S_LEN + s0) * ICH + i;
    const float* gp  = sgate + (size_t)(b * S_LEN + s0) * ICH + i;
    const float* Bp  = ssmp + (size_t)(b * S_LEN + s0) * 80 + 48 + n4 * 4;
    const float* Cp  = Bp + 16;
    const bool last_chunk = (c == NCH - 1);
    #pragma unroll 4
    for (int t = 0; t < CHS; ++t) {
        float dtv = dtp[(size_t)t * ICH];
        float hv  = hp[(size_t)t * ICH];
        float4 Bv = *(const float4*)(Bp + (size_t)t * 80);
        float4 Cv = *(const float4*)(Cp + (size_t)t * 80);
        float x = dtv * hv;
        float dA0 = exp2f(Apr[0] * dtv);
        float dA1 = exp2f(Apr[1] * dtv);
        float dA2 = exp2f(Apr[2] * dtv);
        float dA3 = exp2f(Apr[3] * dtv);
        st[0] = fmaf(dA0, st[0], x * Bv.x);
        st[1] = fmaf(dA1, st[1], x * Bv.y);
        st[2] = fmaf(dA2, st[2], x * Bv.z);
        st[3] = fmaf(dA3, st[3], x * Bv.w);
        float yp = st[0] * Cv.x + st[1] * Cv.y + st[2] * Cv.z + st[3] * Cv.w;
        yp += __shfl_xor(yp, 1, 4);
        yp += __shfl_xor(yp, 2, 4);
        if (n4 == 0) {
            float g = gp[(size_t)t * ICH];
            float yv = fmaf(hv, Dv, yp) * g;
            if (last_chunk && t == CHS - 1) yv *= fgv;
            dtp[(size_t)t * ICH] = yv;
        }
    }
}

// ---------------- K6: out_proj GEMM: [4096,1536] @ [768,1536]^T -> out [4096][768]
__global__ __launch_bounds__(256) void k6_outproj(
    const float* __restrict__ Y,   // [M][I]
    const float* __restrict__ W,   // [768][I]
    float* __restrict__ out)       // [M][768]
{
    __shared__ float4 As[64][5];
    __shared__ float4 Bs[64][5];
    const int tid = threadIdx.x;
    const int tn = tid & 15;
    const int tm = tid >> 4;
    const int m0 = blockIdx.x * 64;
    const int n0 = blockIdx.y * 64;
    const int lrow = tid >> 2, lc4 = tid & 3;
    float acc[4][4] = {};
    for (int k0 = 0; k0 < ICH; k0 += 16) {
        As[lrow][lc4] = *(const float4*)(Y + (size_t)(m0 + lrow) * ICH + k0 + lc4 * 4);
        Bs[lrow][lc4] = *(const float4*)(W + (size_t)(n0 + lrow) * ICH + k0 + lc4 * 4);
        __syncthreads();
        #pragma unroll
        for (int kk4 = 0; kk4 < 4; ++kk4) {
            float4 a[4], b[4];
            #pragma unroll
            for (int i = 0; i < 4; ++i) a[i] = As[tm + 16 * i][kk4];
            #pragma unroll
            for (int j = 0; j < 4; ++j) b[j] = Bs[tn + 16 * j][kk4];
            #pragma unroll
            for (int i = 0; i < 4; ++i)
                #pragma unroll
                for (int j = 0; j < 4; ++j)
                    acc[i][j] += a[i].x * b[j].x + a[i].y * b[j].y +
                                 a[i].z * b[j].z + a[i].w * b[j].w;
        }
        __syncthreads();
    }
    #pragma unroll
    for (int i = 0; i < 4; ++i) {
        int m = m0 + tm + 16 * i;
        #pragma unroll
        for (int j = 0; j < 4; ++j)
            out[(size_t)m * DMODEL + n0 + tn + 16 * j] = acc[i][j];
    }
}

extern "C" void kernel_launch(void* const* d_in, const int* in_sizes, int n_in,
                              void* d_out, int out_size, void* d_ws, size_t ws_size,
                              hipStream_t stream) {
    const float* X     = (const float*)d_in[0];
    const float* W1    = (const float*)d_in[1];
    const float* CW    = (const float*)d_in[2];
    const float* CB    = (const float*)d_in[3];
    const float* XW    = (const float*)d_in[4];
    const float* DTW   = (const float*)d_in[5];
    const float* DTB   = (const float*)d_in[6];
    const float* ALOG  = (const float*)d_in[7];
    const float* DD    = (const float*)d_in[8];
    const float* OW    = (const float*)d_in[9];
    const float* ALPHA = (const float*)d_in[10];
    const float* FG    = (const float*)d_in[11];
    float* out = (float*)d_out;

    float* ws = (float*)d_ws;
    const size_t NBI = (size_t)MROWS * ICH;       // 6,291,456
    float* hidden = ws;
    float* sgate  = hidden + NBI;
    float* hbuf   = sgate + NBI;
    float* dtbuf  = hbuf + NBI;                    // dt, then y in place
    float* ssmp   = dtbuf + NBI;                   // 4096*80
    // chunk summaries overlay dead hidden buffer (3 x 1.57M = 4.72M <= 6.29M floats)
    const size_t SEG = (size_t)2 * ICH * NST * NCH;  // 1,572,864
    float* PArr = hidden;
    float* SfA  = hidden + SEG;
    float* CIn  = hidden + 2 * SEG;

    hipMemsetAsync(ssmp, 0, (size_t)MROWS * 80 * sizeof(float), stream);
    k1_inproj<<<dim3(64, 48), 256, 0, stream>>>(X, W1, hidden, sgate);
    k2_conv<<<dim3((MROWS * 384) / 256), 256, 0, stream>>>(hidden, CW, CB, hbuf);
    k3_xproj<<<dim3(64, 4), 256, 0, stream>>>(hbuf, XW, ssmp);
    k4_dt<<<dim3(64, 24), 256, 0, stream>>>(ssmp, DTW, DTB, ALPHA, dtbuf);
    k5a_chunk<<<dim3(24, NCH, 2), 256, 0, stream>>>(dtbuf, hbuf, ssmp, ALOG, PArr, SfA);
    k5b_carry<<<dim3(192), 256, 0, stream>>>(PArr, SfA, CIn);
    k5c_emit<<<dim3(24, NCH, 2), 256, 0, stream>>>(dtbuf, hbuf, sgate, ssmp, ALOG, DD, FG, CIn);
    k6_outproj<<<dim3(64, 12), 256, 0, stream>>>(dtbuf, OW, out);
}

// Round 4
// 420.977 us; speedup vs baseline: 2.9979x; 1.9153x over previous
//
#include <hip/hip_runtime.h>
#include <math.h>

// AdaptedMixer — Round 4: k1/k6 -> fp16 MFMA (16x16x32_f16, 128x128 tiles).
// B=2 S=2048 Dm=768 I=1536 N=16 R=48 K=4.  M = B*S = 4096.
// Precision: fp16 inputs w/ fp32 MFMA accumulate; est. final absmax ~2e-6 vs 8.39e-6 threshold.
// ws (floats): hidden | sgate | h | dt | ssmp ; halves region R1 (Xh|W1h, reused as yh) ; OWh.

static constexpr int S_LEN  = 2048;
static constexpr int DMODEL = 768;
static constexpr int ICH    = 1536;
static constexpr int NST    = 16;
static constexpr int MROWS  = 4096;   // B*S
static constexpr int NCH    = 32;     // scan chunks
static constexpr int CHS    = 64;     // steps per chunk

typedef _Float16 f16;
typedef f16 f16x8 __attribute__((ext_vector_type(8)));
typedef f16 f16x4 __attribute__((ext_vector_type(4)));
typedef float f32x4 __attribute__((ext_vector_type(4)));

__device__ __forceinline__ float silu_f(float x) {
    return x / (1.0f + __expf(-x));
}

// ---------------- cvt: fp32 -> fp16, 4 elems/thread
__global__ __launch_bounds__(256) void cvt_h(
    const float* __restrict__ s, f16* __restrict__ d)
{
    int i = (blockIdx.x * 256 + threadIdx.x) * 4;
    float4 v = *(const float4*)(s + i);
    f16x4 o = { (f16)v.x, (f16)v.y, (f16)v.z, (f16)v.w };
    *(f16x4*)(d + i) = o;
}

// ---------------- K1: in_proj fp16 MFMA GEMM [4096,768] @ [3072,768]^T
// tile 128x128, 4 waves in 2x2 grid, fused hidden/silu(gate) split epilogue.
__global__ __launch_bounds__(256) void k1m(
    const f16* __restrict__ Xh,    // [4096][768]
    const f16* __restrict__ Wh,    // [3072][768]
    float* __restrict__ hidden,    // [M][I]
    float* __restrict__ sgate)     // [M][I] (silu applied)
{
    __shared__ __align__(16) f16 As[128 * 32];
    __shared__ __align__(16) f16 Bs[128 * 32];
    const int tid = threadIdx.x;
    const int lane = tid & 63, wave = tid >> 6;
    const int quad = lane >> 4, l16 = lane & 15;
    const int wm = wave & 1, wn = wave >> 1;
    const int m0 = blockIdx.x * 128, n0 = blockIdx.y * 128;
    const int srow = tid >> 2, sc8 = (tid & 3) * 8;

    f32x4 acc[4][4] = {};
    const f16* Ag = Xh + (size_t)(m0 + srow) * 768 + sc8;
    const f16* Bg = Wh + (size_t)(n0 + srow) * 768 + sc8;
    for (int k0 = 0; k0 < 768; k0 += 32) {
        __syncthreads();
        *(f16x8*)&As[srow * 32 + sc8]        = *(const f16x8*)(Ag + k0);
        *(f16x8*)&As[(srow + 64) * 32 + sc8] = *(const f16x8*)(Ag + (size_t)64 * 768 + k0);
        *(f16x8*)&Bs[srow * 32 + sc8]        = *(const f16x8*)(Bg + k0);
        *(f16x8*)&Bs[(srow + 64) * 32 + sc8] = *(const f16x8*)(Bg + (size_t)64 * 768 + k0);
        __syncthreads();
        f16x8 af[4], bf[4];
        #pragma unroll
        for (int mi = 0; mi < 4; ++mi)
            af[mi] = *(const f16x8*)&As[(wm * 64 + mi * 16 + l16) * 32 + quad * 8];
        #pragma unroll
        for (int ni = 0; ni < 4; ++ni)
            bf[ni] = *(const f16x8*)&Bs[(wn * 64 + ni * 16 + l16) * 32 + quad * 8];
        #pragma unroll
        for (int mi = 0; mi < 4; ++mi)
            #pragma unroll
            for (int ni = 0; ni < 4; ++ni)
                acc[mi][ni] = __builtin_amdgcn_mfma_f32_16x16x32_f16(
                    af[mi], bf[ni], acc[mi][ni], 0, 0, 0);
    }
    const bool isGate = (n0 >= ICH);
    float* outp = isGate ? sgate : hidden;
    const int e0 = (isGate ? (n0 - ICH) : n0) + wn * 64 + l16;
    #pragma unroll
    for (int mi = 0; mi < 4; ++mi) {
        #pragma unroll
        for (int ni = 0; ni < 4; ++ni) {
            #pragma unroll
            for (int r = 0; r < 4; ++r) {
                int m = m0 + wm * 64 + mi * 16 + quad * 4 + r;
                int e = e0 + ni * 16;
                float v = acc[mi][ni][r];
                if (isGate) v = silu_f(v);
                outp[(size_t)m * ICH + e] = v;
            }
        }
    }
}

// ---------------- K2: causal depthwise conv (K=4) + bias + silu, [M][I] layout
__global__ __launch_bounds__(256) void k2_conv(
    const float* __restrict__ hidden,  // [M][I]
    const float* __restrict__ conv_w,  // [I][4]
    const float* __restrict__ conv_b,  // [I]
    float* __restrict__ h)             // [M][I]
{
    int idx = blockIdx.x * 256 + threadIdx.x;      // over M * (I/4)
    int i4 = idx % 384;
    int m  = idx / 384;
    int s  = m & (S_LEN - 1);
    const float* base = hidden + (size_t)m * ICH + i4 * 4;
    const int c0 = i4 * 4;
    float4 wa = *(const float4*)(conv_w + (c0 + 0) * 4);
    float4 wb = *(const float4*)(conv_w + (c0 + 1) * 4);
    float4 wc = *(const float4*)(conv_w + (c0 + 2) * 4);
    float4 wd = *(const float4*)(conv_w + (c0 + 3) * 4);
    float4 bv = *(const float4*)(conv_b + c0);
    float4 z = {0.f, 0.f, 0.f, 0.f};
    float4 x0 = *(const float4*)(base);
    float4 x1 = (s >= 1) ? *(const float4*)(base - ICH)     : z;
    float4 x2 = (s >= 2) ? *(const float4*)(base - 2 * ICH) : z;
    float4 x3 = (s >= 3) ? *(const float4*)(base - 3 * ICH) : z;
    float4 r;
    r.x = bv.x + wa.x * x3.x + wa.y * x2.x + wa.z * x1.x + wa.w * x0.x;
    r.y = bv.y + wb.x * x3.y + wb.y * x2.y + wb.z * x1.y + wb.w * x0.y;
    r.z = bv.z + wc.x * x3.z + wc.y * x2.z + wc.z * x1.z + wc.w * x0.z;
    r.w = bv.w + wd.x * x3.w + wd.y * x2.w + wd.z * x1.w + wd.w * x0.w;
    r.x = silu_f(r.x); r.y = silu_f(r.y); r.z = silu_f(r.z); r.w = silu_f(r.w);
    *(float4*)(h + (size_t)m * ICH + i4 * 4) = r;
}

// ---------------- K3: x_proj GEMM: ssmp[m][e] += h[m][:] . xw[e][:], K-split x4 atomics
__global__ __launch_bounds__(256) void k3_xproj(
    const float* __restrict__ h,   // [M][I]
    const float* __restrict__ xw,  // [80][I]
    float* __restrict__ ssmp)      // [M][80], pre-zeroed
{
    __shared__ float4 As[64][5];   // [m][k4]
    __shared__ float4 Bs[80][5];   // [e][k4]
    const int tid = threadIdx.x;
    const int tm = tid >> 4;       // m group 0..15
    const int te = tid & 15;       // e lane 0..15
    const int m0 = blockIdx.x * 64;
    const int k_beg = blockIdx.y * 384;
    const int lrow = tid >> 2, lc4 = tid & 3;
    float4 acc[4][5] = {};
    for (int k0 = k_beg; k0 < k_beg + 384; k0 += 16) {
        As[lrow][lc4] = *(const float4*)(h + (size_t)(m0 + lrow) * ICH + k0 + lc4 * 4);
        for (int t = tid; t < 320; t += 256)
            Bs[t >> 2][t & 3] = *(const float4*)(xw + (size_t)(t >> 2) * ICH + k0 + (t & 3) * 4);
        __syncthreads();
        #pragma unroll
        for (int kk4 = 0; kk4 < 4; ++kk4) {
            float4 a[4], b[5];
            #pragma unroll
            for (int i = 0; i < 4; ++i) a[i] = As[tm + 16 * i][kk4];
            #pragma unroll
            for (int j = 0; j < 5; ++j) b[j] = Bs[te + 16 * j][kk4];
            #pragma unroll
            for (int i = 0; i < 4; ++i)
                #pragma unroll
                for (int j = 0; j < 5; ++j) {
                    acc[i][j].x += a[i].x * b[j].x; acc[i][j].y += a[i].y * b[j].y;
                    acc[i][j].z += a[i].z * b[j].z; acc[i][j].w += a[i].w * b[j].w;
                }
        }
        __syncthreads();
    }
    #pragma unroll
    for (int i = 0; i < 4; ++i) {
        int m = m0 + tm + 16 * i;
        #pragma unroll
        for (int j = 0; j < 5; ++j) {
            float v = acc[i][j].x + acc[i][j].y + acc[i][j].z + acc[i][j].w;
            atomicAdd(ssmp + (size_t)m * 80 + te + 16 * j, v);
        }
    }
}

// ---------------- K4: dt = softplus(ts @ dtw^T + b), alpha at s=S-1, write [M][I]
__global__ __launch_bounds__(256) void k4_dt(
    const float* __restrict__ ssmp,   // [M][80] (ts = cols 0..47)
    const float* __restrict__ dtw,    // [I][48]
    const float* __restrict__ dtb,    // [I]
    const float* __restrict__ alpha,  // [I]
    float* __restrict__ dt)           // [M][I]
{
    __shared__ float4 Ts[64][13];
    __shared__ float4 Ws[64][13];
    const int tid = threadIdx.x;
    const int tm = tid >> 4;
    const int te = tid & 15;
    const int m0 = blockIdx.x * 64;
    const int n0 = blockIdx.y * 64;
    for (int t = tid; t < 768; t += 256) {
        int row = t / 12, c4 = t % 12;
        Ts[row][c4] = *(const float4*)(ssmp + (size_t)(m0 + row) * 80 + c4 * 4);
        Ws[row][c4] = *(const float4*)(dtw + (size_t)(n0 + row) * 48 + c4 * 4);
    }
    __syncthreads();
    float acc[4][4] = {};
    #pragma unroll
    for (int kk4 = 0; kk4 < 12; ++kk4) {
        float4 a[4], b[4];
        #pragma unroll
        for (int i = 0; i < 4; ++i) a[i] = Ts[tm + 16 * i][kk4];
        #pragma unroll
        for (int j = 0; j < 4; ++j) b[j] = Ws[te + 16 * j][kk4];
        #pragma unroll
        for (int i = 0; i < 4; ++i)
            #pragma unroll
            for (int j = 0; j < 4; ++j)
                acc[i][j] += a[i].x * b[j].x + a[i].y * b[j].y +
                             a[i].z * b[j].z + a[i].w * b[j].w;
    }
    #pragma unroll
    for (int i = 0; i < 4; ++i) {
        int m = m0 + tm + 16 * i;
        int s = m & (S_LEN - 1);
        #pragma unroll
        for (int j = 0; j < 4; ++j) {
            int e = n0 + te + 16 * j;
            float x = acc[i][j] + dtb[e];
            float sp = (x > 20.0f) ? x : log1pf(expf(x));
            if (s == S_LEN - 1) sp *= alpha[e];
            dt[(size_t)m * ICH + e] = sp;
        }
    }
}

// ---------------- K5a: scan phase A — per-chunk summary
__global__ __launch_bounds__(256) void k5a_chunk(
    const float* __restrict__ dt,    // [M][I]
    const float* __restrict__ h,     // [M][I]
    const float* __restrict__ ssmp,  // [M][80]: B cols 48..63
    const float* __restrict__ A_log, // [I][16]
    float* __restrict__ PArr,        // [B*I*16][32]
    float* __restrict__ SfArr)       // [B*I*16][32]
{
    const int tid = threadIdx.x;
    const int n4 = tid & 3;
    const int il = tid >> 2;
    const int i = blockIdx.x * 64 + il;
    const int c = blockIdx.y;
    const int b = blockIdx.z;
    const int s0 = c * CHS;
    float4 alv = *(const float4*)(A_log + i * NST + n4 * 4);
    const float L2E = 1.44269504088896f;
    float Apr[4] = { -expf(alv.x) * L2E, -expf(alv.y) * L2E,
                     -expf(alv.z) * L2E, -expf(alv.w) * L2E };
    float st[4] = {0.f, 0.f, 0.f, 0.f};
    float P[4] = {1.f, 1.f, 1.f, 1.f};
    const float* dtp = dt + (size_t)(b * S_LEN + s0) * ICH + i;
    const float* hp  = h  + (size_t)(b * S_LEN + s0) * ICH + i;
    const float* Bp  = ssmp + (size_t)(b * S_LEN + s0) * 80 + 48 + n4 * 4;
    #pragma unroll 4
    for (int t = 0; t < CHS; ++t) {
        float dtv = dtp[(size_t)t * ICH];
        float hv  = hp[(size_t)t * ICH];
        float4 Bv = *(const float4*)(Bp + (size_t)t * 80);
        float x = dtv * hv;
        float dA0 = exp2f(Apr[0] * dtv);
        float dA1 = exp2f(Apr[1] * dtv);
        float dA2 = exp2f(Apr[2] * dtv);
        float dA3 = exp2f(Apr[3] * dtv);
        P[0] *= dA0; P[1] *= dA1; P[2] *= dA2; P[3] *= dA3;
        st[0] = fmaf(dA0, st[0], x * Bv.x);
        st[1] = fmaf(dA1, st[1], x * Bv.y);
        st[2] = fmaf(dA2, st[2], x * Bv.z);
        st[3] = fmaf(dA3, st[3], x * Bv.w);
    }
    size_t base = ((size_t)(b * ICH + i) * NST + n4 * 4) * NCH + c;
    #pragma unroll
    for (int j = 0; j < 4; ++j) {
        PArr[base + (size_t)j * NCH]  = P[j];
        SfArr[base + (size_t)j * NCH] = st[j];
    }
}

// ---------------- K5b: combine chunk summaries into carry-in per chunk
__global__ __launch_bounds__(256) void k5b_carry(
    const float* __restrict__ PArr,
    const float* __restrict__ SfArr,
    float* __restrict__ CIn)
{
    int idx = blockIdx.x * 256 + threadIdx.x;   // over B*I*16 = 49152
    size_t base = (size_t)idx * NCH;
    float carry = 0.f;
    #pragma unroll
    for (int c = 0; c < NCH; ++c) {
        CIn[base + c] = carry;
        carry = fmaf(PArr[base + c], carry, SfArr[base + c]);
    }
}

// ---------------- K5c: replay chunk with carry-in, emit y as fp16 into yh
__global__ __launch_bounds__(256) void k5c_emit(
    const float* __restrict__ dt,    // [M][I]
    const float* __restrict__ h,     // [M][I]
    const float* __restrict__ sgate, // [M][I]
    const float* __restrict__ ssmp,  // [M][80]: B 48..63, C 64..79
    const float* __restrict__ A_log, // [I][16]
    const float* __restrict__ Dp,    // [I]
    const float* __restrict__ fg,    // [I]
    const float* __restrict__ CIn,   // [B*I*16][32]
    f16* __restrict__ yh)            // [M][I] fp16
{
    const int tid = threadIdx.x;
    const int n4 = tid & 3;
    const int il = tid >> 2;
    const int i = blockIdx.x * 64 + il;
    const int c = blockIdx.y;
    const int b = blockIdx.z;
    const int s0 = c * CHS;
    float4 alv = *(const float4*)(A_log + i * NST + n4 * 4);
    const float L2E = 1.44269504088896f;
    float Apr[4] = { -expf(alv.x) * L2E, -expf(alv.y) * L2E,
                     -expf(alv.z) * L2E, -expf(alv.w) * L2E };
    const float Dv = Dp[i];
    const float fgv = fg[i];
    size_t cbase = ((size_t)(b * ICH + i) * NST + n4 * 4) * NCH + c;
    float st[4] = { CIn[cbase], CIn[cbase + NCH], CIn[cbase + 2 * NCH], CIn[cbase + 3 * NCH] };
    const float* dtp = dt    + (size_t)(b * S_LEN + s0) * ICH + i;
    const float* hp  = h     + (size_t)(b * S_LEN + s0) * ICH + i;
    const float* gp  = sgate + (size_t)(b * S_LEN + s0) * ICH + i;
    const float* Bp  = ssmp + (size_t)(b * S_LEN + s0) * 80 + 48 + n4 * 4;
    const float* Cp  = Bp + 16;
    f16* yp_out = yh + (size_t)(b * S_LEN + s0) * ICH + i;
    const bool last_chunk = (c == NCH - 1);
    #pragma unroll 4
    for (int t = 0; t < CHS; ++t) {
        float dtv = dtp[(size_t)t * ICH];
        float hv  = hp[(size_t)t * ICH];
        float4 Bv = *(const float4*)(Bp + (size_t)t * 80);
        float4 Cv = *(const float4*)(Cp + (size_t)t * 80);
        float x = dtv * hv;
        float dA0 = exp2f(Apr[0] * dtv);
        float dA1 = exp2f(Apr[1] * dtv);
        float dA2 = exp2f(Apr[2] * dtv);
        float dA3 = exp2f(Apr[3] * dtv);
        st[0] = fmaf(dA0, st[0], x * Bv.x);
        st[1] = fmaf(dA1, st[1], x * Bv.y);
        st[2] = fmaf(dA2, st[2], x * Bv.z);
        st[3] = fmaf(dA3, st[3], x * Bv.w);
        float yp = st[0] * Cv.x + st[1] * Cv.y + st[2] * Cv.z + st[3] * Cv.w;
        yp += __shfl_xor(yp, 1, 4);
        yp += __shfl_xor(yp, 2, 4);
        if (n4 == 0) {
            float g = gp[(size_t)t * ICH];
            float yv = fmaf(hv, Dv, yp) * g;
            if (last_chunk && t == CHS - 1) yv *= fgv;
            yp_out[(size_t)t * ICH] = (f16)yv;
        }
    }
}

// ---------------- K6: out_proj fp16 MFMA GEMM [4096,1536] @ [768,1536]^T -> out fp32
__global__ __launch_bounds__(256) void k6m(
    const f16* __restrict__ Yh,    // [4096][1536]
    const f16* __restrict__ Wh,    // [768][1536]
    float* __restrict__ out)       // [M][768]
{
    __shared__ __align__(16) f16 As[128 * 32];
    __shared__ __align__(16) f16 Bs[128 * 32];
    const int tid = threadIdx.x;
    const int lane = tid & 63, wave = tid >> 6;
    const int quad = lane >> 4, l16 = lane & 15;
    const int wm = wave & 1, wn = wave >> 1;
    const int m0 = blockIdx.x * 128, n0 = blockIdx.y * 128;
    const int srow = tid >> 2, sc8 = (tid & 3) * 8;

    f32x4 acc[4][4] = {};
    const f16* Ag = Yh + (size_t)(m0 + srow) * ICH + sc8;
    const f16* Bg = Wh + (size_t)(n0 + srow) * ICH + sc8;
    for (int k0 = 0; k0 < ICH; k0 += 32) {
        __syncthreads();
        *(f16x8*)&As[srow * 32 + sc8]        = *(const f16x8*)(Ag + k0);
        *(f16x8*)&As[(srow + 64) * 32 + sc8] = *(const f16x8*)(Ag + (size_t)64 * ICH + k0);
        *(f16x8*)&Bs[srow * 32 + sc8]        = *(const f16x8*)(Bg + k0);
        *(f16x8*)&Bs[(srow + 64) * 32 + sc8] = *(const f16x8*)(Bg + (size_t)64 * ICH + k0);
        __syncthreads();
        f16x8 af[4], bf[4];
        #pragma unroll
        for (int mi = 0; mi < 4; ++mi)
            af[mi] = *(const f16x8*)&As[(wm * 64 + mi * 16 + l16) * 32 + quad * 8];
        #pragma unroll
        for (int ni = 0; ni < 4; ++ni)
            bf[ni] = *(const f16x8*)&Bs[(wn * 64 + ni * 16 + l16) * 32 + quad * 8];
        #pragma unroll
        for (int mi = 0; mi < 4; ++mi)
            #pragma unroll
            for (int ni = 0; ni < 4; ++ni)
                acc[mi][ni] = __builtin_amdgcn_mfma_f32_16x16x32_f16(
                    af[mi], bf[ni], acc[mi][ni], 0, 0, 0);
    }
    #pragma unroll
    for (int mi = 0; mi < 4; ++mi) {
        #pragma unroll
        for (int ni = 0; ni < 4; ++ni) {
            #pragma unroll
            for (int r = 0; r < 4; ++r) {
                int m = m0 + wm * 64 + mi * 16 + quad * 4 + r;
                int d = n0 + wn * 64 + ni * 16 + l16;
                out[(size_t)m * DMODEL + d] = acc[mi][ni][r];
            }
        }
    }
}

extern "C" void kernel_launch(void* const* d_in, const int* in_sizes, int n_in,
                              void* d_out, int out_size, void* d_ws, size_t ws_size,
                              hipStream_t stream) {
    const float* X     = (const float*)d_in[0];
    const float* W1    = (const float*)d_in[1];
    const float* CW    = (const float*)d_in[2];
    const float* CB    = (const float*)d_in[3];
    const float* XW    = (const float*)d_in[4];
    const float* DTW   = (const float*)d_in[5];
    const float* DTB   = (const float*)d_in[6];
    const float* ALOG  = (const float*)d_in[7];
    const float* DD    = (const float*)d_in[8];
    const float* OW    = (const float*)d_in[9];
    const float* ALPHA = (const float*)d_in[10];
    const float* FG    = (const float*)d_in[11];
    float* out = (float*)d_out;

    float* ws = (float*)d_ws;
    const size_t NBI = (size_t)MROWS * ICH;        // 6,291,456
    float* hidden = ws;
    float* sgate  = hidden + NBI;
    float* hbuf   = sgate + NBI;
    float* dtbuf  = hbuf + NBI;
    float* ssmp   = dtbuf + NBI;                   // 4096*80
    // halves region R1: [Xh | W1h] before k5c, reused as yh after (sized max = NBI halves)
    f16* R1  = (f16*)(ssmp + (size_t)MROWS * 80);
    f16* Xh  = R1;                                  // 4096*768
    f16* W1h = R1 + (size_t)MROWS * DMODEL;         // 3072*768
    f16* yh  = R1;                                  // 4096*1536 (overlays Xh|W1h)
    f16* OWh = R1 + NBI;                            // 768*1536, lives until k6
    // scan chunk summaries overlay dead hidden buffer
    const size_t SEG = (size_t)2 * ICH * NST * NCH; // 1,572,864
    float* PArr = hidden;
    float* SfA  = hidden + SEG;
    float* CIn  = hidden + 2 * SEG;

    hipMemsetAsync(ssmp, 0, (size_t)MROWS * 80 * sizeof(float), stream);
    cvt_h<<<dim3(3072), 256, 0, stream>>>(X,  Xh);    // 4096*768  /1024
    cvt_h<<<dim3(2304), 256, 0, stream>>>(W1, W1h);   // 3072*768  /1024
    cvt_h<<<dim3(1152), 256, 0, stream>>>(OW, OWh);   // 768*1536  /1024
    k1m<<<dim3(32, 24), 256, 0, stream>>>(Xh, W1h, hidden, sgate);
    k2_conv<<<dim3((MROWS * 384) / 256), 256, 0, stream>>>(hidden, CW, CB, hbuf);
    k3_xproj<<<dim3(64, 4), 256, 0, stream>>>(hbuf, XW, ssmp);
    k4_dt<<<dim3(64, 24), 256, 0, stream>>>(ssmp, DTW, DTB, ALPHA, dtbuf);
    k5a_chunk<<<dim3(24, NCH, 2), 256, 0, stream>>>(dtbuf, hbuf, ssmp, ALOG, PArr, SfA);
    k5b_carry<<<dim3(192), 256, 0, stream>>>(PArr, SfA, CIn);
    k5c_emit<<<dim3(24, NCH, 2), 256, 0, stream>>>(dtbuf, hbuf, sgate, ssmp, ALOG, DD, FG, CIn, yh);
    k6m<<<dim3(32, 6), 256, 0, stream>>>(yh, OWh, out);
}

// Round 5
// 361.383 us; speedup vs baseline: 3.4922x; 1.1649x over previous
//
#include <hip/hip_runtime.h>
#include <math.h>

// AdaptedMixer — Round 5: k4 -> fp16 MFMA (K=48 pad 64, inline cvt, fast softplus);
// +LDS pad (stride 40 f16) in k1m/k6m to kill 8-way fragment-read bank conflicts.
// B=2 S=2048 Dm=768 I=1536 N=16 R=48 K=4.  M = B*S = 4096.

static constexpr int S_LEN  = 2048;
static constexpr int DMODEL = 768;
static constexpr int ICH    = 1536;
static constexpr int NST    = 16;
static constexpr int MROWS  = 4096;   // B*S
static constexpr int NCH    = 32;     // scan chunks
static constexpr int CHS    = 64;     // steps per chunk

typedef _Float16 f16;
typedef f16 f16x8 __attribute__((ext_vector_type(8)));
typedef f16 f16x4 __attribute__((ext_vector_type(4)));
typedef float f32x4 __attribute__((ext_vector_type(4)));

__device__ __forceinline__ float silu_f(float x) {
    return x / (1.0f + __expf(-x));
}

// ---------------- cvt: fp32 -> fp16, 4 elems/thread
__global__ __launch_bounds__(256) void cvt_h(
    const float* __restrict__ s, f16* __restrict__ d)
{
    int i = (blockIdx.x * 256 + threadIdx.x) * 4;
    float4 v = *(const float4*)(s + i);
    f16x4 o = { (f16)v.x, (f16)v.y, (f16)v.z, (f16)v.w };
    *(f16x4*)(d + i) = o;
}

// ---------------- K1: in_proj fp16 MFMA GEMM [4096,768] @ [3072,768]^T
// tile 128x128, 4 waves 2x2, LDS row stride 40 f16 (pad 8), fused silu-gate epilogue.
__global__ __launch_bounds__(256) void k1m(
    const f16* __restrict__ Xh,    // [4096][768]
    const f16* __restrict__ Wh,    // [3072][768]
    float* __restrict__ hidden,    // [M][I]
    float* __restrict__ sgate)     // [M][I] (silu applied)
{
    __shared__ __align__(16) f16 As[128 * 40];
    __shared__ __align__(16) f16 Bs[128 * 40];
    const int tid = threadIdx.x;
    const int lane = tid & 63, wave = tid >> 6;
    const int quad = lane >> 4, l16 = lane & 15;
    const int wm = wave & 1, wn = wave >> 1;
    const int m0 = blockIdx.x * 128, n0 = blockIdx.y * 128;
    const int srow = tid >> 2, sc8 = (tid & 3) * 8;

    f32x4 acc[4][4] = {};
    const f16* Ag = Xh + (size_t)(m0 + srow) * 768 + sc8;
    const f16* Bg = Wh + (size_t)(n0 + srow) * 768 + sc8;
    for (int k0 = 0; k0 < 768; k0 += 32) {
        __syncthreads();
        *(f16x8*)&As[srow * 40 + sc8]        = *(const f16x8*)(Ag + k0);
        *(f16x8*)&As[(srow + 64) * 40 + sc8] = *(const f16x8*)(Ag + (size_t)64 * 768 + k0);
        *(f16x8*)&Bs[srow * 40 + sc8]        = *(const f16x8*)(Bg + k0);
        *(f16x8*)&Bs[(srow + 64) * 40 + sc8] = *(const f16x8*)(Bg + (size_t)64 * 768 + k0);
        __syncthreads();
        f16x8 af[4], bf[4];
        #pragma unroll
        for (int mi = 0; mi < 4; ++mi)
            af[mi] = *(const f16x8*)&As[(wm * 64 + mi * 16 + l16) * 40 + quad * 8];
        #pragma unroll
        for (int ni = 0; ni < 4; ++ni)
            bf[ni] = *(const f16x8*)&Bs[(wn * 64 + ni * 16 + l16) * 40 + quad * 8];
        #pragma unroll
        for (int mi = 0; mi < 4; ++mi)
            #pragma unroll
            for (int ni = 0; ni < 4; ++ni)
                acc[mi][ni] = __builtin_amdgcn_mfma_f32_16x16x32_f16(
                    af[mi], bf[ni], acc[mi][ni], 0, 0, 0);
    }
    const bool isGate = (n0 >= ICH);
    float* outp = isGate ? sgate : hidden;
    const int e0 = (isGate ? (n0 - ICH) : n0) + wn * 64 + l16;
    #pragma unroll
    for (int mi = 0; mi < 4; ++mi) {
        #pragma unroll
        for (int ni = 0; ni < 4; ++ni) {
            #pragma unroll
            for (int r = 0; r < 4; ++r) {
                int m = m0 + wm * 64 + mi * 16 + quad * 4 + r;
                int e = e0 + ni * 16;
                float v = acc[mi][ni][r];
                if (isGate) v = silu_f(v);
                outp[(size_t)m * ICH + e] = v;
            }
        }
    }
}

// ---------------- K2: causal depthwise conv (K=4) + bias + silu, [M][I] layout
__global__ __launch_bounds__(256) void k2_conv(
    const float* __restrict__ hidden,  // [M][I]
    const float* __restrict__ conv_w,  // [I][4]
    const float* __restrict__ conv_b,  // [I]
    float* __restrict__ h)             // [M][I]
{
    int idx = blockIdx.x * 256 + threadIdx.x;      // over M * (I/4)
    int i4 = idx % 384;
    int m  = idx / 384;
    int s  = m & (S_LEN - 1);
    const float* base = hidden + (size_t)m * ICH + i4 * 4;
    const int c0 = i4 * 4;
    float4 wa = *(const float4*)(conv_w + (c0 + 0) * 4);
    float4 wb = *(const float4*)(conv_w + (c0 + 1) * 4);
    float4 wc = *(const float4*)(conv_w + (c0 + 2) * 4);
    float4 wd = *(const float4*)(conv_w + (c0 + 3) * 4);
    float4 bv = *(const float4*)(conv_b + c0);
    float4 z = {0.f, 0.f, 0.f, 0.f};
    float4 x0 = *(const float4*)(base);
    float4 x1 = (s >= 1) ? *(const float4*)(base - ICH)     : z;
    float4 x2 = (s >= 2) ? *(const float4*)(base - 2 * ICH) : z;
    float4 x3 = (s >= 3) ? *(const float4*)(base - 3 * ICH) : z;
    float4 r;
    r.x = bv.x + wa.x * x3.x + wa.y * x2.x + wa.z * x1.x + wa.w * x0.x;
    r.y = bv.y + wb.x * x3.y + wb.y * x2.y + wb.z * x1.y + wb.w * x0.y;
    r.z = bv.z + wc.x * x3.z + wc.y * x2.z + wc.z * x1.z + wc.w * x0.z;
    r.w = bv.w + wd.x * x3.w + wd.y * x2.w + wd.z * x1.w + wd.w * x0.w;
    r.x = silu_f(r.x); r.y = silu_f(r.y); r.z = silu_f(r.z); r.w = silu_f(r.w);
    *(float4*)(h + (size_t)m * ICH + i4 * 4) = r;
}

// ---------------- K3: x_proj GEMM: ssmp[m][e] += h[m][:] . xw[e][:], K-split x4 atomics
__global__ __launch_bounds__(256) void k3_xproj(
    const float* __restrict__ h,   // [M][I]
    const float* __restrict__ xw,  // [80][I]
    float* __restrict__ ssmp)      // [M][80], pre-zeroed
{
    __shared__ float4 As[64][5];   // [m][k4]
    __shared__ float4 Bs[80][5];   // [e][k4]
    const int tid = threadIdx.x;
    const int tm = tid >> 4;       // m group 0..15
    const int te = tid & 15;       // e lane 0..15
    const int m0 = blockIdx.x * 64;
    const int k_beg = blockIdx.y * 384;
    const int lrow = tid >> 2, lc4 = tid & 3;
    float4 acc[4][5] = {};
    for (int k0 = k_beg; k0 < k_beg + 384; k0 += 16) {
        As[lrow][lc4] = *(const float4*)(h + (size_t)(m0 + lrow) * ICH + k0 + lc4 * 4);
        for (int t = tid; t < 320; t += 256)
            Bs[t >> 2][t & 3] = *(const float4*)(xw + (size_t)(t >> 2) * ICH + k0 + (t & 3) * 4);
        __syncthreads();
        #pragma unroll
        for (int kk4 = 0; kk4 < 4; ++kk4) {
            float4 a[4], b[5];
            #pragma unroll
            for (int i = 0; i < 4; ++i) a[i] = As[tm + 16 * i][kk4];
            #pragma unroll
            for (int j = 0; j < 5; ++j) b[j] = Bs[te + 16 * j][kk4];
            #pragma unroll
            for (int i = 0; i < 4; ++i)
                #pragma unroll
                for (int j = 0; j < 5; ++j) {
                    acc[i][j].x += a[i].x * b[j].x; acc[i][j].y += a[i].y * b[j].y;
                    acc[i][j].z += a[i].z * b[j].z; acc[i][j].w += a[i].w * b[j].w;
                }
        }
        __syncthreads();
    }
    #pragma unroll
    for (int i = 0; i < 4; ++i) {
        int m = m0 + tm + 16 * i;
        #pragma unroll
        for (int j = 0; j < 5; ++j) {
            float v = acc[i][j].x + acc[i][j].y + acc[i][j].z + acc[i][j].w;
            atomicAdd(ssmp + (size_t)m * 80 + te + 16 * j, v);
        }
    }
}

// ---------------- K4: dt = softplus(ts @ dtw^T + b) via fp16 MFMA, K=48 padded to 64.
// tile 128x128, single LDS stage (whole K), inline fp32->fp16 cvt during staging.
__global__ __launch_bounds__(256) void k4m(
    const float* __restrict__ ssmp,   // [M][80] (ts = cols 0..47)
    const float* __restrict__ dtw,    // [I][48]
    const float* __restrict__ dtb,    // [I]
    const float* __restrict__ alpha,  // [I]
    float* __restrict__ dt)           // [M][I]
{
    __shared__ __align__(16) f16 As[128 * 72];   // [row][72] (64 K + 8 pad)
    __shared__ __align__(16) f16 Bs[128 * 72];
    const int tid = threadIdx.x;
    const int lane = tid & 63, wave = tid >> 6;
    const int quad = lane >> 4, l16 = lane & 15;
    const int wm = wave & 1, wn = wave >> 1;
    const int m0 = blockIdx.x * 128, n0 = blockIdx.y * 128;
    const int srow = tid >> 1;          // 0..127
    const int shalf = tid & 1;          // 0..1 -> cols [0,24) or [24,48)

    {   // stage A (ts) and B (dtw), cvt to fp16, zero-pad cols 48..63
        const float* sa = ssmp + (size_t)(m0 + srow) * 80 + shalf * 24;
        const float* sb = dtw + (size_t)(n0 + srow) * 48 + shalf * 24;
        f16* da = &As[srow * 72 + shalf * 24];
        f16* db = &Bs[srow * 72 + shalf * 24];
        #pragma unroll
        for (int j = 0; j < 6; ++j) {
            float4 va = *(const float4*)(sa + 4 * j);
            float4 vb = *(const float4*)(sb + 4 * j);
            f16x4 oa = { (f16)va.x, (f16)va.y, (f16)va.z, (f16)va.w };
            f16x4 ob = { (f16)vb.x, (f16)vb.y, (f16)vb.z, (f16)vb.w };
            *(f16x4*)(da + 4 * j) = oa;
            *(f16x4*)(db + 4 * j) = ob;
        }
        if (shalf) {
            f16x8 z = {};
            *(f16x8*)&As[srow * 72 + 48] = z;
            *(f16x8*)&As[srow * 72 + 56] = z;
            *(f16x8*)&Bs[srow * 72 + 48] = z;
            *(f16x8*)&Bs[srow * 72 + 56] = z;
        }
    }
    __syncthreads();

    f32x4 acc[4][4] = {};
    #pragma unroll
    for (int ks = 0; ks < 2; ++ks) {
        f16x8 af[4], bf[4];
        #pragma unroll
        for (int mi = 0; mi < 4; ++mi)
            af[mi] = *(const f16x8*)&As[(wm * 64 + mi * 16 + l16) * 72 + ks * 32 + quad * 8];
        #pragma unroll
        for (int ni = 0; ni < 4; ++ni)
            bf[ni] = *(const f16x8*)&Bs[(wn * 64 + ni * 16 + l16) * 72 + ks * 32 + quad * 8];
        #pragma unroll
        for (int mi = 0; mi < 4; ++mi)
            #pragma unroll
            for (int ni = 0; ni < 4; ++ni)
                acc[mi][ni] = __builtin_amdgcn_mfma_f32_16x16x32_f16(
                    af[mi], bf[ni], acc[mi][ni], 0, 0, 0);
    }

    #pragma unroll
    for (int ni = 0; ni < 4; ++ni) {
        int e = n0 + wn * 64 + ni * 16 + l16;
        float bias = dtb[e];
        float al = alpha[e];
        #pragma unroll
        for (int mi = 0; mi < 4; ++mi) {
            #pragma unroll
            for (int r = 0; r < 4; ++r) {
                int m = m0 + wm * 64 + mi * 16 + quad * 4 + r;
                float x = acc[mi][ni][r] + bias;
                float sp = (x > 20.0f) ? x : __logf(1.0f + __expf(x));
                if ((m & (S_LEN - 1)) == S_LEN - 1) sp *= al;
                dt[(size_t)m * ICH + e] = sp;
            }
        }
    }
}

// ---------------- K5a: scan phase A — per-chunk summary
__global__ __launch_bounds__(256) void k5a_chunk(
    const float* __restrict__ dt,    // [M][I]
    const float* __restrict__ h,     // [M][I]
    const float* __restrict__ ssmp,  // [M][80]: B cols 48..63
    const float* __restrict__ A_log, // [I][16]
    float* __restrict__ PArr,        // [B*I*16][32]
    float* __restrict__ SfArr)       // [B*I*16][32]
{
    const int tid = threadIdx.x;
    const int n4 = tid & 3;
    const int il = tid >> 2;
    const int i = blockIdx.x * 64 + il;
    const int c = blockIdx.y;
    const int b = blockIdx.z;
    const int s0 = c * CHS;
    float4 alv = *(const float4*)(A_log + i * NST + n4 * 4);
    const float L2E = 1.44269504088896f;
    float Apr[4] = { -expf(alv.x) * L2E, -expf(alv.y) * L2E,
                     -expf(alv.z) * L2E, -expf(alv.w) * L2E };
    float st[4] = {0.f, 0.f, 0.f, 0.f};
    float P[4] = {1.f, 1.f, 1.f, 1.f};
    const float* dtp = dt + (size_t)(b * S_LEN + s0) * ICH + i;
    const float* hp  = h  + (size_t)(b * S_LEN + s0) * ICH + i;
    const float* Bp  = ssmp + (size_t)(b * S_LEN + s0) * 80 + 48 + n4 * 4;
    #pragma unroll 4
    for (int t = 0; t < CHS; ++t) {
        float dtv = dtp[(size_t)t * ICH];
        float hv  = hp[(size_t)t * ICH];
        float4 Bv = *(const float4*)(Bp + (size_t)t * 80);
        float x = dtv * hv;
        float dA0 = exp2f(Apr[0] * dtv);
        float dA1 = exp2f(Apr[1] * dtv);
        float dA2 = exp2f(Apr[2] * dtv);
        float dA3 = exp2f(Apr[3] * dtv);
        P[0] *= dA0; P[1] *= dA1; P[2] *= dA2; P[3] *= dA3;
        st[0] = fmaf(dA0, st[0], x * Bv.x);
        st[1] = fmaf(dA1, st[1], x * Bv.y);
        st[2] = fmaf(dA2, st[2], x * Bv.z);
        st[3] = fmaf(dA3, st[3], x * Bv.w);
    }
    size_t base = ((size_t)(b * ICH + i) * NST + n4 * 4) * NCH + c;
    #pragma unroll
    for (int j = 0; j < 4; ++j) {
        PArr[base + (size_t)j * NCH]  = P[j];
        SfArr[base + (size_t)j * NCH] = st[j];
    }
}

// ---------------- K5b: combine chunk summaries into carry-in per chunk
__global__ __launch_bounds__(256) void k5b_carry(
    const float* __restrict__ PArr,
    const float* __restrict__ SfArr,
    float* __restrict__ CIn)
{
    int idx = blockIdx.x * 256 + threadIdx.x;   // over B*I*16 = 49152
    size_t base = (size_t)idx * NCH;
    float carry = 0.f;
    #pragma unroll
    for (int c = 0; c < NCH; ++c) {
        CIn[base + c] = carry;
        carry = fmaf(PArr[base + c], carry, SfArr[base + c]);
    }
}

// ---------------- K5c: replay chunk with carry-in, emit y as fp16 into yh
__global__ __launch_bounds__(256) void k5c_emit(
    const float* __restrict__ dt,    // [M][I]
    const float* __restrict__ h,     // [M][I]
    const float* __restrict__ sgate, // [M][I]
    const float* __restrict__ ssmp,  // [M][80]: B 48..63, C 64..79
    const float* __restrict__ A_log, // [I][16]
    const float* __restrict__ Dp,    // [I]
    const float* __restrict__ fg,    // [I]
    const float* __restrict__ CIn,   // [B*I*16][32]
    f16* __restrict__ yh)            // [M][I] fp16
{
    const int tid = threadIdx.x;
    const int n4 = tid & 3;
    const int il = tid >> 2;
    const int i = blockIdx.x * 64 + il;
    const int c = blockIdx.y;
    const int b = blockIdx.z;
    const int s0 = c * CHS;
    float4 alv = *(const float4*)(A_log + i * NST + n4 * 4);
    const float L2E = 1.44269504088896f;
    float Apr[4] = { -expf(alv.x) * L2E, -expf(alv.y) * L2E,
                     -expf(alv.z) * L2E, -expf(alv.w) * L2E };
    const float Dv = Dp[i];
    const float fgv = fg[i];
    size_t cbase = ((size_t)(b * ICH + i) * NST + n4 * 4) * NCH + c;
    float st[4] = { CIn[cbase], CIn[cbase + NCH], CIn[cbase + 2 * NCH], CIn[cbase + 3 * NCH] };
    const float* dtp = dt    + (size_t)(b * S_LEN + s0) * ICH + i;
    const float* hp  = h     + (size_t)(b * S_LEN + s0) * ICH + i;
    const float* gp  = sgate + (size_t)(b * S_LEN + s0) * ICH + i;
    const float* Bp  = ssmp + (size_t)(b * S_LEN + s0) * 80 + 48 + n4 * 4;
    const float* Cp  = Bp + 16;
    f16* yp_out = yh + (size_t)(b * S_LEN + s0) * ICH + i;
    const bool last_chunk = (c == NCH - 1);
    #pragma unroll 4
    for (int t = 0; t < CHS; ++t) {
        float dtv = dtp[(size_t)t * ICH];
        float hv  = hp[(size_t)t * ICH];
        float4 Bv = *(const float4*)(Bp + (size_t)t * 80);
        float4 Cv = *(const float4*)(Cp + (size_t)t * 80);
        float x = dtv * hv;
        float dA0 = exp2f(Apr[0] * dtv);
        float dA1 = exp2f(Apr[1] * dtv);
        float dA2 = exp2f(Apr[2] * dtv);
        float dA3 = exp2f(Apr[3] * dtv);
        st[0] = fmaf(dA0, st[0], x * Bv.x);
        st[1] = fmaf(dA1, st[1], x * Bv.y);
        st[2] = fmaf(dA2, st[2], x * Bv.z);
        st[3] = fmaf(dA3, st[3], x * Bv.w);
        float yp = st[0] * Cv.x + st[1] * Cv.y + st[2] * Cv.z + st[3] * Cv.w;
        yp += __shfl_xor(yp, 1, 4);
        yp += __shfl_xor(yp, 2, 4);
        if (n4 == 0) {
            float g = gp[(size_t)t * ICH];
            float yv = fmaf(hv, Dv, yp) * g;
            if (last_chunk && t == CHS - 1) yv *= fgv;
            yp_out[(size_t)t * ICH] = (f16)yv;
        }
    }
}

// ---------------- K6: out_proj fp16 MFMA GEMM [4096,1536] @ [768,1536]^T -> out fp32
__global__ __launch_bounds__(256) void k6m(
    const f16* __restrict__ Yh,    // [4096][1536]
    const f16* __restrict__ Wh,    // [768][1536]
    float* __restrict__ out)       // [M][768]
{
    __shared__ __align__(16) f16 As[128 * 40];
    __shared__ __align__(16) f16 Bs[128 * 40];
    const int tid = threadIdx.x;
    const int lane = tid & 63, wave = tid >> 6;
    const int quad = lane >> 4, l16 = lane & 15;
    const int wm = wave & 1, wn = wave >> 1;
    const int m0 = blockIdx.x * 128, n0 = blockIdx.y * 128;
    const int srow = tid >> 2, sc8 = (tid & 3) * 8;

    f32x4 acc[4][4] = {};
    const f16* Ag = Yh + (size_t)(m0 + srow) * ICH + sc8;
    const f16* Bg = Wh + (size_t)(n0 + srow) * ICH + sc8;
    for (int k0 = 0; k0 < ICH; k0 += 32) {
        __syncthreads();
        *(f16x8*)&As[srow * 40 + sc8]        = *(const f16x8*)(Ag + k0);
        *(f16x8*)&As[(srow + 64) * 40 + sc8] = *(const f16x8*)(Ag + (size_t)64 * ICH + k0);
        *(f16x8*)&Bs[srow * 40 + sc8]        = *(const f16x8*)(Bg + k0);
        *(f16x8*)&Bs[(srow + 64) * 40 + sc8] = *(const f16x8*)(Bg + (size_t)64 * ICH + k0);
        __syncthreads();
        f16x8 af[4], bf[4];
        #pragma unroll
        for (int mi = 0; mi < 4; ++mi)
            af[mi] = *(const f16x8*)&As[(wm * 64 + mi * 16 + l16) * 40 + quad * 8];
        #pragma unroll
        for (int ni = 0; ni < 4; ++ni)
            bf[ni] = *(const f16x8*)&Bs[(wn * 64 + ni * 16 + l16) * 40 + quad * 8];
        #pragma unroll
        for (int mi = 0; mi < 4; ++mi)
            #pragma unroll
            for (int ni = 0; ni < 4; ++ni)
                acc[mi][ni] = __builtin_amdgcn_mfma_f32_16x16x32_f16(
                    af[mi], bf[ni], acc[mi][ni], 0, 0, 0);
    }
    #pragma unroll
    for (int mi = 0; mi < 4; ++mi) {
        #pragma unroll
        for (int ni = 0; ni < 4; ++ni) {
            #pragma unroll
            for (int r = 0; r < 4; ++r) {
                int m = m0 + wm * 64 + mi * 16 + quad * 4 + r;
                int d = n0 + wn * 64 + ni * 16 + l16;
                out[(size_t)m * DMODEL + d] = acc[mi][ni][r];
            }
        }
    }
}

extern "C" void kernel_launch(void* const* d_in, const int* in_sizes, int n_in,
                              void* d_out, int out_size, void* d_ws, size_t ws_size,
                              hipStream_t stream) {
    const float* X     = (const float*)d_in[0];
    const float* W1    = (const float*)d_in[1];
    const float* CW    = (const float*)d_in[2];
    const float* CB    = (const float*)d_in[3];
    const float* XW    = (const float*)d_in[4];
    const float* DTW   = (const float*)d_in[5];
    const float* DTB   = (const float*)d_in[6];
    const float* ALOG  = (const float*)d_in[7];
    const float* DD    = (const float*)d_in[8];
    const float* OW    = (const float*)d_in[9];
    const float* ALPHA = (const float*)d_in[10];
    const float* FG    = (const float*)d_in[11];
    float* out = (float*)d_out;

    float* ws = (float*)d_ws;
    const size_t NBI = (size_t)MROWS * ICH;        // 6,291,456
    float* hidden = ws;
    float* sgate  = hidden + NBI;
    float* hbuf   = sgate + NBI;
    float* dtbuf  = hbuf + NBI;
    float* ssmp   = dtbuf + NBI;                   // 4096*80
    // halves region R1: [Xh | W1h] before k5c, reused as yh after (sized max = NBI halves)
    f16* R1  = (f16*)(ssmp + (size_t)MROWS * 80);
    f16* Xh  = R1;                                  // 4096*768
    f16* W1h = R1 + (size_t)MROWS * DMODEL;         // 3072*768
    f16* yh  = R1;                                  // 4096*1536 (overlays Xh|W1h)
    f16* OWh = R1 + NBI;                            // 768*1536, lives until k6
    // scan chunk summaries overlay dead hidden buffer
    const size_t SEG = (size_t)2 * ICH * NST * NCH; // 1,572,864
    float* PArr = hidden;
    float* SfA  = hidden + SEG;
    float* CIn  = hidden + 2 * SEG;

    hipMemsetAsync(ssmp, 0, (size_t)MROWS * 80 * sizeof(float), stream);
    cvt_h<<<dim3(3072), 256, 0, stream>>>(X,  Xh);    // 4096*768  /1024
    cvt_h<<<dim3(2304), 256, 0, stream>>>(W1, W1h);   // 3072*768  /1024
    cvt_h<<<dim3(1152), 256, 0, stream>>>(OW, OWh);   // 768*1536  /1024
    k1m<<<dim3(32, 24), 256, 0, stream>>>(Xh, W1h, hidden, sgate);
    k2_conv<<<dim3((MROWS * 384) / 256), 256, 0, stream>>>(hidden, CW, CB, hbuf);
    k3_xproj<<<dim3(64, 4), 256, 0, stream>>>(hbuf, XW, ssmp);
    k4m<<<dim3(32, 12), 256, 0, stream>>>(ssmp, DTW, DTB, ALPHA, dtbuf);
    k5a_chunk<<<dim3(24, NCH, 2), 256, 0, stream>>>(dtbuf, hbuf, ssmp, ALOG, PArr, SfA);
    k5b_carry<<<dim3(192), 256, 0, stream>>>(PArr, SfA, CIn);
    k5c_emit<<<dim3(24, NCH, 2), 256, 0, stream>>>(dtbuf, hbuf, sgate, ssmp, ALOG, DD, FG, CIn, yh);
    k6m<<<dim3(32, 6), 256, 0, stream>>>(yh, OWh, out);
}